// Round 3
// baseline (25.782 us; speedup 1.0000x reference)
//
#include <hip/hip_runtime.h>
#include <hip/hip_bf16.h>

// MF dot-product: out[i] = dot(table[x[i,0]], table[x[i,1] + N_USERS])
// x is int32. 16 lanes per group; each group handles 4 consecutive rows to
// raise memory-level parallelism (8 independent float4 row-loads per thread).

#define N_USERS_OFFSET 1000000

__global__ __launch_bounds__(256) void mf_dot_kernel4(
    const int* __restrict__ x,            // (batch, 2) int32
    const float* __restrict__ table,      // (2e6, 64) fp32
    float* __restrict__ out,              // (batch,) fp32
    int batch)
{
    int gid   = blockIdx.x * blockDim.x + threadIdx.x;
    int group = gid >> 4;
    int lane  = gid & 15;
    int i0    = group * 4;                // first of 4 rows for this group
    if (i0 >= batch) return;

    // 8 indices (4 rows × 2) via two int4 loads
    const int4* xv = reinterpret_cast<const int4*>(x);
    int4 xa = xv[group * 2];              // rows i0, i0+1
    int4 xb = xv[group * 2 + 1];          // rows i0+2, i0+3

    const float4* t4 = reinterpret_cast<const float4*>(table);

    // row base pointers (float4 granules): table row r starts at t4[r*16]
    long long u0 = (long long)xa.x * 16 + lane;
    long long v0 = ((long long)xa.y + N_USERS_OFFSET) * 16 + lane;
    long long u1 = (long long)xa.z * 16 + lane;
    long long v1 = ((long long)xa.w + N_USERS_OFFSET) * 16 + lane;
    long long u2 = (long long)xb.x * 16 + lane;
    long long v2 = ((long long)xb.y + N_USERS_OFFSET) * 16 + lane;
    long long u3 = (long long)xb.z * 16 + lane;
    long long v3 = ((long long)xb.w + N_USERS_OFFSET) * 16 + lane;

    // issue all 8 row loads (independent, stay in flight together)
    float4 a0 = t4[u0], b0 = t4[v0];
    float4 a1 = t4[u1], b1 = t4[v1];
    float4 a2 = t4[u2], b2 = t4[v2];
    float4 a3 = t4[u3], b3 = t4[v3];

    float s0 = a0.x*b0.x + a0.y*b0.y + a0.z*b0.z + a0.w*b0.w;
    float s1 = a1.x*b1.x + a1.y*b1.y + a1.z*b1.z + a1.w*b1.w;
    float s2 = a2.x*b2.x + a2.y*b2.y + a2.z*b2.z + a2.w*b2.w;
    float s3 = a3.x*b3.x + a3.y*b3.y + a3.z*b3.z + a3.w*b3.w;

    // reduce each across the 16-lane group
    #pragma unroll
    for (int d = 1; d < 16; d <<= 1) {
        s0 += __shfl_xor(s0, d, 64);
        s1 += __shfl_xor(s1, d, 64);
        s2 += __shfl_xor(s2, d, 64);
        s3 += __shfl_xor(s3, d, 64);
    }

    if (lane == 0) {
        // i0 is a multiple of 4 -> aligned float4 store
        *reinterpret_cast<float4*>(out + i0) = make_float4(s0, s1, s2, s3);
    }
}

extern "C" void kernel_launch(void* const* d_in, const int* in_sizes, int n_in,
                              void* d_out, int out_size, void* d_ws, size_t ws_size,
                              hipStream_t stream) {
    const int* x         = (const int*)d_in[0];         // (BATCH, 2) int32
    const float* table   = (const float*)d_in[1];       // (2e6, 64) fp32
    float* out           = (float*)d_out;               // (BATCH,) fp32

    int batch = in_sizes[0] / 2;                        // 262144

    int threads = 256;
    long long groups = (batch + 3) / 4;                 // 4 rows per 16-lane group
    long long total  = groups * 16;
    int blocks = (int)((total + threads - 1) / threads);

    mf_dot_kernel4<<<blocks, threads, 0, stream>>>(x, table, out, batch);
}